// Round 7
// baseline (333.775 us; speedup 1.0000x reference)
//
#include <hip/hip_runtime.h>

#define T_LEN 512
#define HD    32
#define FUT   60
#define ELW   16      // batch elements per wave (16x16 MFMA tile rows)
#define ROWH  40      // h_lds row stride in f16 (80B: 16B-aligned, bank-rotating)

typedef float    f32x4 __attribute__((ext_vector_type(4)));
typedef _Float16 f16x2 __attribute__((ext_vector_type(2)));
typedef _Float16 f16x8 __attribute__((ext_vector_type(8)));

#define MF(a, b, c) __builtin_amdgcn_mfma_f32_16x16x32_f16((a), (b), (c), 0, 0, 0)

// cvt_pkrtz returns __fp16x2; bit-identical to f16x2 -> bit_cast
__device__ __forceinline__ f16x2 pkrtz(float a, float b) {
    return __builtin_bit_cast(f16x2, __builtin_amdgcn_cvt_pkrtz(a, b));
}

__device__ __forceinline__ float dot2(f16x2 a, f16x2 b, float c) {
    return __builtin_amdgcn_fdot2(a, b, c, false);
}
__device__ __forceinline__ float sigmf_(float v) {
    return __builtin_amdgcn_rcpf(1.0f + __expf(-v));
}
__device__ __forceinline__ float tanhf_(float v) {
    return fmaf(2.0f, __builtin_amdgcn_rcpf(1.0f + __expf(-2.0f * v)), -1.0f);
}

// B-fragment of v_mfma_f32_16x16x32_f16 from row-major W[96][32] (gate-row n, k):
// lane l holds W[rowoff + (l&15)][8*(l>>4) .. +7]  (f32 -> f16)
__device__ __forceinline__ f16x8 loadBfrag(const float* W, int rowoff, int s, int g) {
    const float* p = W + (size_t)(rowoff + s) * HD + g * 8;
    f32x4 a = *(const f32x4*)p;
    f32x4 b = *(const f32x4*)(p + 4);
    f16x8 r;
    r[0] = (_Float16)a[0]; r[1] = (_Float16)a[1]; r[2] = (_Float16)a[2]; r[3] = (_Float16)a[3];
    r[4] = (_Float16)b[0]; r[5] = (_Float16)b[1]; r[6] = (_Float16)b[2]; r[7] = (_Float16)b[3];
    return r;
}
__device__ __forceinline__ f16x8 loadBfragSum(const float* WA, const float* WB,
                                              int rowoff, int s, int g) {
    const float* pa = WA + (size_t)(rowoff + s) * HD + g * 8;
    const float* pb = WB + (size_t)(rowoff + s) * HD + g * 8;
    f32x4 a0 = *(const f32x4*)pa, a1 = *(const f32x4*)(pa + 4);
    f32x4 b0 = *(const f32x4*)pb, b1 = *(const f32x4*)(pb + 4);
    f16x8 r;
    r[0] = (_Float16)(a0[0] + b0[0]); r[1] = (_Float16)(a0[1] + b0[1]);
    r[2] = (_Float16)(a0[2] + b0[2]); r[3] = (_Float16)(a0[3] + b0[3]);
    r[4] = (_Float16)(a1[0] + b1[0]); r[5] = (_Float16)(a1[1] + b1[1]);
    r[6] = (_Float16)(a1[2] + b1[2]); r[7] = (_Float16)(a1[3] + b1[3]);
    return r;
}
__device__ __forceinline__ f32x4 splat4(float v) { return (f32x4){v, v, v, v}; }

// One wave (64 thr) = 16 batch elements. Per step: G[16x96] via 12 MFMA
// (K=64 over [e_t | h] for r,z; n-gate split e/h). Gates in C-layout
// (col=lane&15, row=(lane>>4)*4+reg). h' transposed C->A layout through a
// tiny LDS tile (8 ds_write_b16 + 1 ds_read_b128, single wave, no barrier).
__global__ __launch_bounds__(64) __attribute__((amdgpu_waves_per_eu(1, 1)))
void gru_encdec(
    const float* __restrict__ x,
    const float* __restrict__ W_emb, const float* __restrict__ b_emb,
    const float* __restrict__ Wih_e, const float* __restrict__ Whh_e,
    const float* __restrict__ bih_e, const float* __restrict__ bhh_e,
    const float* __restrict__ Wih_d, const float* __restrict__ Whh_d,
    const float* __restrict__ bih_d, const float* __restrict__ bhh_d,
    const float* __restrict__ W_out, const float* __restrict__ b_out,
    float* __restrict__ y)
{
    __shared__ __align__(16) _Float16 h_lds[ELW * ROWH + 8];

    const int l = threadIdx.x;
    const int s = l & 15;    // tile row (batch) for A / tile col for B,C
    const int g = l >> 4;    // k-group (A,B) / row-group (C)
    const int w = blockIdx.x;

    // ---- encoder B-fragments: 12 x 4 VGPR ----
    const f16x8 Bxr0 = loadBfrag(Wih_e,  0, s, g), Bxr1 = loadBfrag(Wih_e, 16, s, g);
    const f16x8 Bxz0 = loadBfrag(Wih_e, 32, s, g), Bxz1 = loadBfrag(Wih_e, 48, s, g);
    const f16x8 Bxn0 = loadBfrag(Wih_e, 64, s, g), Bxn1 = loadBfrag(Wih_e, 80, s, g);
    const f16x8 Bhr0 = loadBfrag(Whh_e,  0, s, g), Bhr1 = loadBfrag(Whh_e, 16, s, g);
    const f16x8 Bhz0 = loadBfrag(Whh_e, 32, s, g), Bhz1 = loadBfrag(Whh_e, 48, s, g);
    const f16x8 Bhn0 = loadBfrag(Whh_e, 64, s, g), Bhn1 = loadBfrag(Whh_e, 80, s, g);

    // ---- encoder bias tiles (MFMA C-input; col = s + 16*tp) ----
    const f32x4 Tbr0 = splat4(bih_e[s]      + bhh_e[s]);
    const f32x4 Tbr1 = splat4(bih_e[16 + s] + bhh_e[16 + s]);
    const f32x4 Tbz0 = splat4(bih_e[32 + s] + bhh_e[32 + s]);
    const f32x4 Tbz1 = splat4(bih_e[48 + s] + bhh_e[48 + s]);
    const f32x4 Tbnx0 = splat4(bih_e[64 + s]), Tbnx1 = splat4(bih_e[80 + s]);
    const f32x4 Tbnh0 = splat4(bhh_e[64 + s]), Tbnh1 = splat4(bhh_e[80 + s]);

    // ---- embedder weights: lane's 8 hidden rows (k = g*8+kk), d-pairs as f16 ----
    f16x2 wemb[8][2]; float bemb8[8];
    #pragma unroll
    for (int kk = 0; kk < 8; ++kk) {
        const f32x4 v = *(const f32x4*)(W_emb + (size_t)(g * 8 + kk) * 4);
        wemb[kk][0] = pkrtz(v[0], v[1]);
        wemb[kk][1] = pkrtz(v[2], v[3]);
        bemb8[kk] = b_emb[g * 8 + kk];
    }

    // ---- x stream: lane s owns element b = w*16+s (lanes 16.. duplicate; L1 merges) ----
    const f32x4* xb = (const f32x4*)x + (size_t)(w * ELW + s) * T_LEN;
    f32x4 xb0 = xb[0], xb1 = xb[1];

    f16x8 hA = {};                       // h in A-layout (f16), h0 = 0
    f32x4 hc0 = {0.f, 0.f, 0.f, 0.f};    // h in C-layout (f32), tiles 0/1
    f32x4 hc1 = {0.f, 0.f, 0.f, 0.f};

    _Float16* hw = &h_lds[(4 * g) * ROWH + s];          // transpose write base
    const _Float16* hr = &h_lds[s * ROWH + g * 8];      // A-frag read base

    auto enc_step = [&](const f32x4 xv) {
        // e_t fragment in-register: e = relu(W_emb @ x + b), f16 A-layout
        const f16x2 xp01 = pkrtz(xv[0], xv[1]);
        const f16x2 xp23 = pkrtz(xv[2], xv[3]);
        float ev[8];
        #pragma unroll
        for (int kk = 0; kk < 8; ++kk)
            ev[kk] = fmaxf(dot2(wemb[kk][0], xp01, dot2(wemb[kk][1], xp23, bemb8[kk])), 0.0f);
        f16x8 eA;
        #pragma unroll
        for (int q = 0; q < 4; ++q) {
            const f16x2 pk = pkrtz(ev[2 * q], ev[2 * q + 1]);
            eA[2 * q] = pk[0]; eA[2 * q + 1] = pk[1];
        }
        // 12 MFMA: bias tiles as C-in (no accumulator init)
        f32x4 cr0 = MF(eA, Bxr0, Tbr0);  cr0 = MF(hA, Bhr0, cr0);
        f32x4 cr1 = MF(eA, Bxr1, Tbr1);  cr1 = MF(hA, Bhr1, cr1);
        f32x4 cz0 = MF(eA, Bxz0, Tbz0);  cz0 = MF(hA, Bhz0, cz0);
        f32x4 cz1 = MF(eA, Bxz1, Tbz1);  cz1 = MF(hA, Bhz1, cz1);
        const f32x4 cnx0 = MF(eA, Bxn0, Tbnx0), cnx1 = MF(eA, Bxn1, Tbnx1);
        const f32x4 cnh0 = MF(hA, Bhn0, Tbnh0), cnh1 = MF(hA, Bhn1, Tbnh1);
        // gates, elementwise in C-layout
        #pragma unroll
        for (int i = 0; i < 4; ++i) {
            const float r0 = sigmf_(cr0[i]), z0 = sigmf_(cz0[i]);
            const float n0 = tanhf_(fmaf(r0, cnh0[i], cnx0[i]));
            hc0[i] = fmaf(z0, hc0[i] - n0, n0);
            const float r1 = sigmf_(cr1[i]), z1 = sigmf_(cz1[i]);
            const float n1 = tanhf_(fmaf(r1, cnh1[i], cnx1[i]));
            hc1[i] = fmaf(z1, hc1[i] - n1, n1);
        }
        // C-layout -> A-layout transpose via LDS (single wave: DS in-order)
        #pragma unroll
        for (int i = 0; i < 4; ++i) {
            hw[i * ROWH]      = (_Float16)hc0[i];
            hw[i * ROWH + 16] = (_Float16)hc1[i];
        }
        hA = *(const f16x8*)hr;
    };

    // ---- encoder: 512 steps, x prefetched 2 ahead ----
    for (int t = 0; t < T_LEN; t += 2) {
        f32x4 xn0 = xb0, xn1 = xb1;
        if (t + 2 < T_LEN) xn0 = xb[t + 2];
        if (t + 3 < T_LEN) xn1 = xb[t + 3];
        enc_step(xb0);
        enc_step(xb1);
        xb0 = xn0; xb1 = xn1;
    }

    // ---- decoder B-fragments (r,z presummed: input == hidden) + W_out ----
    const f16x8 Bdr0 = loadBfragSum(Wih_d, Whh_d,  0, s, g);
    const f16x8 Bdr1 = loadBfragSum(Wih_d, Whh_d, 16, s, g);
    const f16x8 Bdz0 = loadBfragSum(Wih_d, Whh_d, 32, s, g);
    const f16x8 Bdz1 = loadBfragSum(Wih_d, Whh_d, 48, s, g);
    const f16x8 Bdnx0 = loadBfrag(Wih_d, 64, s, g), Bdnx1 = loadBfrag(Wih_d, 80, s, g);
    const f16x8 Bdnh0 = loadBfrag(Whh_d, 64, s, g), Bdnh1 = loadBfrag(Whh_d, 80, s, g);
    f16x8 Bout = {};
    if (s < 4) Bout = loadBfrag(W_out, 0, s, g);
    const f32x4 Tdr0 = splat4(bih_d[s]      + bhh_d[s]);
    const f32x4 Tdr1 = splat4(bih_d[16 + s] + bhh_d[16 + s]);
    const f32x4 Tdz0 = splat4(bih_d[32 + s] + bhh_d[32 + s]);
    const f32x4 Tdz1 = splat4(bih_d[48 + s] + bhh_d[48 + s]);
    const f32x4 Tdnx0 = splat4(bih_d[64 + s]), Tdnx1 = splat4(bih_d[80 + s]);
    const f32x4 Tdnh0 = splat4(bhh_d[64 + s]), Tdnh1 = splat4(bhh_d[80 + s]);
    const f32x4 Tby = splat4(s < 4 ? b_out[s] : 0.0f);

    float* yp = y + ((size_t)(w * ELW + 4 * g) * FUT) * 4 + s;

    // ---- decoder: 60 steps ----
    #pragma unroll 1
    for (int f = 0; f < FUT; ++f) {
        f32x4 cr0 = MF(hA, Bdr0, Tdr0), cr1 = MF(hA, Bdr1, Tdr1);
        f32x4 cz0 = MF(hA, Bdz0, Tdz0), cz1 = MF(hA, Bdz1, Tdz1);
        const f32x4 cnx0 = MF(hA, Bdnx0, Tdnx0), cnx1 = MF(hA, Bdnx1, Tdnx1);
        const f32x4 cnh0 = MF(hA, Bdnh0, Tdnh0), cnh1 = MF(hA, Bdnh1, Tdnh1);
        #pragma unroll
        for (int i = 0; i < 4; ++i) {
            const float r0 = sigmf_(cr0[i]), z0 = sigmf_(cz0[i]);
            const float n0 = tanhf_(fmaf(r0, cnh0[i], cnx0[i]));
            hc0[i] = fmaf(z0, hc0[i] - n0, n0);
            const float r1 = sigmf_(cr1[i]), z1 = sigmf_(cz1[i]);
            const float n1 = tanhf_(fmaf(r1, cnh1[i], cnx1[i]));
            hc1[i] = fmaf(z1, hc1[i] - n1, n1);
        }
        #pragma unroll
        for (int i = 0; i < 4; ++i) {
            hw[i * ROWH]      = (_Float16)hc0[i];
            hw[i * ROWH + 16] = (_Float16)hc1[i];
        }
        hA = *(const f16x8*)hr;
        // y_f[16x4] = h' @ W_out^T + b_out via one MFMA (cols 0-3 valid)
        const f32x4 cy = MF(hA, Bout, Tby);
        if (s < 4) {
            #pragma unroll
            for (int i = 0; i < 4; ++i)
                yp[(size_t)(i * FUT + f) * 4] = cy[i];
        }
    }
}

extern "C" void kernel_launch(void* const* d_in, const int* in_sizes, int n_in,
                              void* d_out, int out_size, void* d_ws, size_t ws_size,
                              hipStream_t stream) {
    (void)in_sizes; (void)n_in; (void)d_ws; (void)ws_size; (void)out_size;
    gru_encdec<<<dim3(2048 / ELW), dim3(64), 0, stream>>>(
        (const float*)d_in[0],                            // x
        (const float*)d_in[1],  (const float*)d_in[2],    // W_emb, b_emb
        (const float*)d_in[3],  (const float*)d_in[4],    // Wih_e, Whh_e
        (const float*)d_in[5],  (const float*)d_in[6],    // bih_e, bhh_e
        (const float*)d_in[7],  (const float*)d_in[8],    // Wih_d, Whh_d
        (const float*)d_in[9],  (const float*)d_in[10],   // bih_d, bhh_d
        (const float*)d_in[11], (const float*)d_in[12],   // W_out, b_out
        (float*)d_out);
}

// Round 8
// 311.923 us; speedup vs baseline: 1.0701x; 1.0701x over previous
//
#include <hip/hip_runtime.h>

#define T_LEN 512
#define HD    32
#define FUT   60
#define ELW   16      // batch elements per wave (16x16 MFMA tile)

typedef float    f32x4 __attribute__((ext_vector_type(4)));
typedef _Float16 f16x2 __attribute__((ext_vector_type(2)));
typedef _Float16 f16x8 __attribute__((ext_vector_type(8)));
typedef unsigned int u32x2 __attribute__((ext_vector_type(2)));

union F16x8U { f16x8 v; f16x2 p[4]; unsigned int d[4]; };

#define MF(a, b, c) __builtin_amdgcn_mfma_f32_16x16x32_f16((a), (b), (c), 0, 0, 0)

__device__ __forceinline__ f16x2 pkrtz(float a, float b) {
    return __builtin_bit_cast(f16x2, __builtin_amdgcn_cvt_pkrtz(a, b));
}
__device__ __forceinline__ unsigned pkbits(float a, float b) {
    return __builtin_bit_cast(unsigned, __builtin_amdgcn_cvt_pkrtz(a, b));
}
__device__ __forceinline__ float dot2(f16x2 a, f16x2 b, float c) {
    return __builtin_amdgcn_fdot2(a, b, c, false);
}
__device__ __forceinline__ float sigmf_(float v) {
    return __builtin_amdgcn_rcpf(1.0f + __expf(-v));
}
__device__ __forceinline__ float tanhf_(float v) {
    return fmaf(2.0f, __builtin_amdgcn_rcpf(1.0f + __expf(-2.0f * v)), -1.0f);
}

// a' = [a_lanes0-31 | b_lanes0-31], b' = [a_lanes32-63 | b_lanes32-63]
__device__ __forceinline__ void swap32(unsigned& a, unsigned& b) {
#if __has_builtin(__builtin_amdgcn_permlane32_swap)
    u32x2 r = __builtin_amdgcn_permlane32_swap(a, b, false, false);
    a = r.x; b = r.y;
#else
    unsigned as = __shfl_xor((int)a, 32, 64), bs = __shfl_xor((int)b, 32, 64);
    const bool hi = (threadIdx.x & 32) != 0;
    unsigned na = hi ? bs : a, nb = hi ? b : as;
    a = na; b = nb;
#endif
}
// per 32-half: a' = [a_g0 | b_g0], b' = [a_g1 | b_g1]  (16-lane groups)
__device__ __forceinline__ void swap16(unsigned& a, unsigned& b) {
#if __has_builtin(__builtin_amdgcn_permlane16_swap)
    u32x2 r = __builtin_amdgcn_permlane16_swap(a, b, false, false);
    a = r.x; b = r.y;
#else
    unsigned as = __shfl_xor((int)a, 16, 64), bs = __shfl_xor((int)b, 16, 64);
    const bool hi = (threadIdx.x & 16) != 0;
    unsigned na = hi ? bs : a, nb = hi ? b : as;
    a = na; b = nb;
#endif
}

// A-fragment (row = l&15, k = 8*(l>>4)..+7) from row-major W[96][32]
__device__ __forceinline__ f16x8 loadAfrag(const float* W, int rowoff, int s, int g) {
    const float* p = W + (size_t)(rowoff + s) * HD + g * 8;
    f32x4 a = *(const f32x4*)p;
    f32x4 b = *(const f32x4*)(p + 4);
    f16x8 r;
    r[0] = (_Float16)a[0]; r[1] = (_Float16)a[1]; r[2] = (_Float16)a[2]; r[3] = (_Float16)a[3];
    r[4] = (_Float16)b[0]; r[5] = (_Float16)b[1]; r[6] = (_Float16)b[2]; r[7] = (_Float16)b[3];
    return r;
}
__device__ __forceinline__ f16x8 loadAfragSum(const float* WA, const float* WB,
                                              int rowoff, int s, int g) {
    const float* pa = WA + (size_t)(rowoff + s) * HD + g * 8;
    const float* pb = WB + (size_t)(rowoff + s) * HD + g * 8;
    f32x4 a0 = *(const f32x4*)pa, a1 = *(const f32x4*)(pa + 4);
    f32x4 b0 = *(const f32x4*)pb, b1 = *(const f32x4*)(pb + 4);
    f16x8 r;
    r[0] = (_Float16)(a0[0] + b0[0]); r[1] = (_Float16)(a0[1] + b0[1]);
    r[2] = (_Float16)(a0[2] + b0[2]); r[3] = (_Float16)(a0[3] + b0[3]);
    r[4] = (_Float16)(a1[0] + b1[0]); r[5] = (_Float16)(a1[1] + b1[1]);
    r[6] = (_Float16)(a1[2] + b1[2]); r[7] = (_Float16)(a1[3] + b1[3]);
    return r;
}
// bias C-tile: [i] = ba[off+4g+i] (+ bb if given)
__device__ __forceinline__ f32x4 biasTile(const float* ba, int off, int g) {
    return *(const f32x4*)(ba + off + 4 * g);
}
__device__ __forceinline__ f32x4 biasTile2(const float* ba, const float* bb, int off, int g) {
    f32x4 a = *(const f32x4*)(ba + off + 4 * g);
    f32x4 b = *(const f32x4*)(bb + off + 4 * g);
    return a + b;
}

// One wave = 16 batch elements. SWAPPED-OPERAND MFMA: C[unit][elem] =
// W(A) x act(B). Per-lane (s = l&15, g = l>>4):
//   A-frag:  W[rowoff+s][8g..8g+7]
//   B-frag:  act[k=8g..8g+7][elem=s]     (same per-lane content as old A-frag)
//   C-tile:  gate[unit=4g+i (+16*tile)][elem=s]
// C->B rearrangement is group-local in {s,s+16,s+32,s+48}: 2x permlane32_swap
// + 2x permlane16_swap (pure VALU) -- NO LDS anywhere in the loop.
__global__ __launch_bounds__(64) __attribute__((amdgpu_waves_per_eu(1, 1)))
void gru_encdec(
    const float* __restrict__ x,
    const float* __restrict__ W_emb, const float* __restrict__ b_emb,
    const float* __restrict__ Wih_e, const float* __restrict__ Whh_e,
    const float* __restrict__ bih_e, const float* __restrict__ bhh_e,
    const float* __restrict__ Wih_d, const float* __restrict__ Whh_d,
    const float* __restrict__ bih_d, const float* __restrict__ bhh_d,
    const float* __restrict__ W_out, const float* __restrict__ b_out,
    float* __restrict__ y)
{
    const int l = threadIdx.x;
    const int s = l & 15;
    const int g = l >> 4;
    const int w = blockIdx.x;

    // ---- encoder A-fragments (weights): 12 x 4 VGPR ----
    const f16x8 Axr0 = loadAfrag(Wih_e,  0, s, g), Axr1 = loadAfrag(Wih_e, 16, s, g);
    const f16x8 Axz0 = loadAfrag(Wih_e, 32, s, g), Axz1 = loadAfrag(Wih_e, 48, s, g);
    const f16x8 Axn0 = loadAfrag(Wih_e, 64, s, g), Axn1 = loadAfrag(Wih_e, 80, s, g);
    const f16x8 Ahr0 = loadAfrag(Whh_e,  0, s, g), Ahr1 = loadAfrag(Whh_e, 16, s, g);
    const f16x8 Ahz0 = loadAfrag(Whh_e, 32, s, g), Ahz1 = loadAfrag(Whh_e, 48, s, g);
    const f16x8 Ahn0 = loadAfrag(Whh_e, 64, s, g), Ahn1 = loadAfrag(Whh_e, 80, s, g);

    // ---- encoder bias C-tiles: row = unit = 4g+i ----
    const f32x4 Tbr0  = biasTile2(bih_e, bhh_e,  0, g), Tbr1 = biasTile2(bih_e, bhh_e, 16, g);
    const f32x4 Tbz0  = biasTile2(bih_e, bhh_e, 32, g), Tbz1 = biasTile2(bih_e, bhh_e, 48, g);
    const f32x4 Tbnx0 = biasTile(bih_e, 64, g), Tbnx1 = biasTile(bih_e, 80, g);
    const f32x4 Tbnh0 = biasTile(bhh_e, 64, g), Tbnh1 = biasTile(bhh_e, 80, g);

    // ---- embedder weights: lane's 8 hidden rows (k = g*8+kk) ----
    f16x2 wemb[8][2]; float bemb8[8];
    #pragma unroll
    for (int kk = 0; kk < 8; ++kk) {
        const f32x4 v = *(const f32x4*)(W_emb + (size_t)(g * 8 + kk) * 4);
        wemb[kk][0] = pkrtz(v[0], v[1]);
        wemb[kk][1] = pkrtz(v[2], v[3]);
        bemb8[kk] = b_emb[g * 8 + kk];
    }

    // ---- x stream: lane s owns element w*16+s (groups duplicate; L1 merges) ----
    const f32x4* xb = (const f32x4*)x + (size_t)(w * ELW + s) * T_LEN;
    f32x4 xb0 = xb[0], xb1 = xb[1];

    F16x8U hB; hB.d[0] = 0; hB.d[1] = 0; hB.d[2] = 0; hB.d[3] = 0;   // h0 = 0
    f32x4 hc0 = {0.f, 0.f, 0.f, 0.f};   // h[unit 4g+i][elem s]   (tile 0)
    f32x4 hc1 = {0.f, 0.f, 0.f, 0.f};   // h[unit 16+4g+i][elem s] (tile 1)

    auto enc_step = [&](const f32x4 xv) {
        // e_t B-fragment in-register: e = relu(W_emb @ x + b)
        const f16x2 xp01 = pkrtz(xv[0], xv[1]);
        const f16x2 xp23 = pkrtz(xv[2], xv[3]);
        float ev[8];
        #pragma unroll
        for (int kk = 0; kk < 8; ++kk)
            ev[kk] = fmaxf(dot2(wemb[kk][0], xp01, dot2(wemb[kk][1], xp23, bemb8[kk])), 0.0f);
        F16x8U eB;
        #pragma unroll
        for (int q = 0; q < 4; ++q)
            eB.d[q] = pkbits(ev[2 * q], ev[2 * q + 1]);
        // 12 MFMA (A=weights, B=activations); e-MFMAs are off the h-chain
        f32x4 cr0 = MF(Axr0, eB.v, Tbr0);  cr0 = MF(Ahr0, hB.v, cr0);
        f32x4 cr1 = MF(Axr1, eB.v, Tbr1);  cr1 = MF(Ahr1, hB.v, cr1);
        f32x4 cz0 = MF(Axz0, eB.v, Tbz0);  cz0 = MF(Ahz0, hB.v, cz0);
        f32x4 cz1 = MF(Axz1, eB.v, Tbz1);  cz1 = MF(Ahz1, hB.v, cz1);
        const f32x4 cnx0 = MF(Axn0, eB.v, Tbnx0), cnx1 = MF(Axn1, eB.v, Tbnx1);
        const f32x4 cnh0 = MF(Ahn0, hB.v, Tbnh0), cnh1 = MF(Ahn1, hB.v, Tbnh1);
        // gates, elementwise in C-layout
        #pragma unroll
        for (int i = 0; i < 4; ++i) {
            const float r0 = sigmf_(cr0[i]), z0 = sigmf_(cz0[i]);
            const float n0 = tanhf_(fmaf(r0, cnh0[i], cnx0[i]));
            hc0[i] = fmaf(z0, hc0[i] - n0, n0);
            const float r1 = sigmf_(cr1[i]), z1 = sigmf_(cz1[i]);
            const float n1 = tanhf_(fmaf(r1, cnh1[i], cnx1[i]));
            hc1[i] = fmaf(z1, hc1[i] - n1, n1);
        }
        // C-layout -> B-fragment via 4 permlane swaps (all-VALU transpose)
        unsigned p0 = pkbits(hc0[0], hc0[1]);   // units (4g, 4g+1)
        unsigned p1 = pkbits(hc0[2], hc0[3]);   // units (4g+2, 4g+3)
        unsigned q0 = pkbits(hc1[0], hc1[1]);   // units (16+4g, 16+4g+1)
        unsigned q1 = pkbits(hc1[2], hc1[3]);
        swap32(p0, q0); swap32(p1, q1);
        swap16(p0, q0); swap16(p1, q1);
        hB.d[0] = p0; hB.d[1] = p1; hB.d[2] = q0; hB.d[3] = q1;
    };

    // ---- encoder: 512 steps, x prefetched 2 ahead ----
    for (int t = 0; t < T_LEN; t += 2) {
        f32x4 xn0 = xb0, xn1 = xb1;
        if (t + 2 < T_LEN) xn0 = xb[t + 2];
        if (t + 3 < T_LEN) xn1 = xb[t + 3];
        enc_step(xb0);
        enc_step(xb1);
        xb0 = xn0; xb1 = xn1;
    }

    // ---- decoder A-fragments (r,z presummed: input == hidden) + W_out ----
    const f16x8 Adr0 = loadAfragSum(Wih_d, Whh_d,  0, s, g);
    const f16x8 Adr1 = loadAfragSum(Wih_d, Whh_d, 16, s, g);
    const f16x8 Adz0 = loadAfragSum(Wih_d, Whh_d, 32, s, g);
    const f16x8 Adz1 = loadAfragSum(Wih_d, Whh_d, 48, s, g);
    const f16x8 Adnx0 = loadAfrag(Wih_d, 64, s, g), Adnx1 = loadAfrag(Wih_d, 80, s, g);
    const f16x8 Adnh0 = loadAfrag(Whh_d, 64, s, g), Adnh1 = loadAfrag(Whh_d, 80, s, g);
    f16x8 Aout = {};
    if (s < 4) Aout = loadAfrag(W_out, 0, s, g);
    const f32x4 Tdr0  = biasTile2(bih_d, bhh_d,  0, g), Tdr1 = biasTile2(bih_d, bhh_d, 16, g);
    const f32x4 Tdz0  = biasTile2(bih_d, bhh_d, 32, g), Tdz1 = biasTile2(bih_d, bhh_d, 48, g);
    const f32x4 Tdnx0 = biasTile(bih_d, 64, g), Tdnx1 = biasTile(bih_d, 80, g);
    const f32x4 Tdnh0 = biasTile(bhh_d, 64, g), Tdnh1 = biasTile(bhh_d, 80, g);
    const f32x4 Tby = (g == 0) ? *(const f32x4*)b_out : (f32x4){0.f, 0.f, 0.f, 0.f};

    // ---- decoder: 60 steps ----
    #pragma unroll 1
    for (int f = 0; f < FUT; ++f) {
        f32x4 cr0 = MF(Adr0, hB.v, Tdr0), cr1 = MF(Adr1, hB.v, Tdr1);
        f32x4 cz0 = MF(Adz0, hB.v, Tdz0), cz1 = MF(Adz1, hB.v, Tdz1);
        const f32x4 cnx0 = MF(Adnx0, hB.v, Tdnx0), cnx1 = MF(Adnx1, hB.v, Tdnx1);
        const f32x4 cnh0 = MF(Adnh0, hB.v, Tdnh0), cnh1 = MF(Adnh1, hB.v, Tdnh1);
        #pragma unroll
        for (int i = 0; i < 4; ++i) {
            const float r0 = sigmf_(cr0[i]), z0 = sigmf_(cz0[i]);
            const float n0 = tanhf_(fmaf(r0, cnh0[i], cnx0[i]));
            hc0[i] = fmaf(z0, hc0[i] - n0, n0);
            const float r1 = sigmf_(cr1[i]), z1 = sigmf_(cz1[i]);
            const float n1 = tanhf_(fmaf(r1, cnh1[i], cnx1[i]));
            hc1[i] = fmaf(z1, hc1[i] - n1, n1);
        }
        unsigned p0 = pkbits(hc0[0], hc0[1]), p1 = pkbits(hc0[2], hc0[3]);
        unsigned q0 = pkbits(hc1[0], hc1[1]), q1 = pkbits(hc1[2], hc1[3]);
        swap32(p0, q0); swap32(p1, q1);
        swap16(p0, q0); swap16(p1, q1);
        hB.d[0] = p0; hB.d[1] = p1; hB.d[2] = q0; hB.d[3] = q1;

        // y_f: C[feat 4g+i][elem s] — valid rows live entirely in g==0 lanes
        const f32x4 cy = MF(Aout, hB.v, Tby);
        if (g == 0)
            *(f32x4*)(y + ((size_t)(w * ELW + s) * FUT + f) * 4) = cy;
    }
}

extern "C" void kernel_launch(void* const* d_in, const int* in_sizes, int n_in,
                              void* d_out, int out_size, void* d_ws, size_t ws_size,
                              hipStream_t stream) {
    (void)in_sizes; (void)n_in; (void)d_ws; (void)ws_size; (void)out_size;
    gru_encdec<<<dim3(2048 / ELW), dim3(64), 0, stream>>>(
        (const float*)d_in[0],                            // x
        (const float*)d_in[1],  (const float*)d_in[2],    // W_emb, b_emb
        (const float*)d_in[3],  (const float*)d_in[4],    // Wih_e, Whh_e
        (const float*)d_in[5],  (const float*)d_in[6],    // bih_e, bhh_e
        (const float*)d_in[7],  (const float*)d_in[8],    // Wih_d, Whh_d
        (const float*)d_in[9],  (const float*)d_in[10],   // bih_d, bhh_d
        (const float*)d_in[11], (const float*)d_in[12],   // W_out, b_out
        (float*)d_out);
}

// Round 9
// 268.040 us; speedup vs baseline: 1.2452x; 1.1637x over previous
//
#include <hip/hip_runtime.h>

#define T_LEN 512
#define HD    32
#define FUT   60
#define ELW   16      // batch elements per wave (16x16 MFMA tile)

typedef float    f32x4 __attribute__((ext_vector_type(4)));
typedef _Float16 f16x2 __attribute__((ext_vector_type(2)));
typedef _Float16 f16x8 __attribute__((ext_vector_type(8)));
typedef unsigned int u32x2 __attribute__((ext_vector_type(2)));

union F16x8U { f16x8 v; f16x2 p[4]; unsigned int d[4]; };

#define MF(a, b, c) __builtin_amdgcn_mfma_f32_16x16x32_f16((a), (b), (c), 0, 0, 0)

#define L2E  1.4426950408889634f
#define N2E  2.8853900817779268f

__device__ __forceinline__ f16x2 pkrtz(float a, float b) {
    return __builtin_bit_cast(f16x2, __builtin_amdgcn_cvt_pkrtz(a, b));
}
__device__ __forceinline__ unsigned pkbits(float a, float b) {
    return __builtin_bit_cast(unsigned, __builtin_amdgcn_cvt_pkrtz(a, b));
}
__device__ __forceinline__ float dot2(f16x2 a, f16x2 b, float c) {
    return __builtin_amdgcn_fdot2(a, b, c, false);
}
__device__ __forceinline__ float exp2f_(float x) {
#if __has_builtin(__builtin_amdgcn_exp2f)
    return __builtin_amdgcn_exp2f(x);
#else
    return __builtin_exp2f(x);
#endif
}
// inputs PRESCALED: u = x*log2e  ->  sigmoid(x); u = x*2log2e -> tanh(x)
__device__ __forceinline__ float sig_s(float u) {
    return __builtin_amdgcn_rcpf(1.0f + exp2f_(-u));
}
__device__ __forceinline__ float tanh_s(float u) {
    return fmaf(2.0f, __builtin_amdgcn_rcpf(1.0f + exp2f_(-u)), -1.0f);
}

__device__ __forceinline__ void swap32(unsigned& a, unsigned& b) {
#if __has_builtin(__builtin_amdgcn_permlane32_swap)
    u32x2 r = __builtin_amdgcn_permlane32_swap(a, b, false, false);
    a = r.x; b = r.y;
#else
    unsigned as = __shfl_xor((int)a, 32, 64), bs = __shfl_xor((int)b, 32, 64);
    const bool hi = (threadIdx.x & 32) != 0;
    unsigned na = hi ? bs : a, nb = hi ? b : as;
    a = na; b = nb;
#endif
}
__device__ __forceinline__ void swap16(unsigned& a, unsigned& b) {
#if __has_builtin(__builtin_amdgcn_permlane16_swap)
    u32x2 r = __builtin_amdgcn_permlane16_swap(a, b, false, false);
    a = r.x; b = r.y;
#else
    unsigned as = __shfl_xor((int)a, 16, 64), bs = __shfl_xor((int)b, 16, 64);
    const bool hi = (threadIdx.x & 16) != 0;
    unsigned na = hi ? bs : a, nb = hi ? b : as;
    a = na; b = nb;
#endif
}

// A-fragment (row = l&15, k = 8*(l>>4)..+7) from row-major W[96][32], scaled
__device__ __forceinline__ f16x8 loadAfrag(const float* W, int rowoff, int s, int g, float sc) {
    const float* p = W + (size_t)(rowoff + s) * HD + g * 8;
    f32x4 a = *(const f32x4*)p;
    f32x4 b = *(const f32x4*)(p + 4);
    f16x8 r;
    r[0] = (_Float16)(a[0]*sc); r[1] = (_Float16)(a[1]*sc);
    r[2] = (_Float16)(a[2]*sc); r[3] = (_Float16)(a[3]*sc);
    r[4] = (_Float16)(b[0]*sc); r[5] = (_Float16)(b[1]*sc);
    r[6] = (_Float16)(b[2]*sc); r[7] = (_Float16)(b[3]*sc);
    return r;
}
__device__ __forceinline__ f16x8 loadAfragSum(const float* WA, const float* WB,
                                              int rowoff, int s, int g, float sc) {
    const float* pa = WA + (size_t)(rowoff + s) * HD + g * 8;
    const float* pb = WB + (size_t)(rowoff + s) * HD + g * 8;
    f32x4 a0 = *(const f32x4*)pa, a1 = *(const f32x4*)(pa + 4);
    f32x4 b0 = *(const f32x4*)pb, b1 = *(const f32x4*)(pb + 4);
    f16x8 r;
    r[0] = (_Float16)((a0[0]+b0[0])*sc); r[1] = (_Float16)((a0[1]+b0[1])*sc);
    r[2] = (_Float16)((a0[2]+b0[2])*sc); r[3] = (_Float16)((a0[3]+b0[3])*sc);
    r[4] = (_Float16)((a1[0]+b1[0])*sc); r[5] = (_Float16)((a1[1]+b1[1])*sc);
    r[6] = (_Float16)((a1[2]+b1[2])*sc); r[7] = (_Float16)((a1[3]+b1[3])*sc);
    return r;
}
__device__ __forceinline__ f32x4 biasTile(const float* ba, int off, int g, float sc) {
    f32x4 a = *(const f32x4*)(ba + off + 4 * g);
    return (f32x4){a[0]*sc, a[1]*sc, a[2]*sc, a[3]*sc};
}
__device__ __forceinline__ f32x4 biasTile2(const float* ba, const float* bb, int off, int g, float sc) {
    f32x4 a = *(const f32x4*)(ba + off + 4 * g);
    f32x4 b = *(const f32x4*)(bb + off + 4 * g);
    return (f32x4){(a[0]+b[0])*sc, (a[1]+b[1])*sc, (a[2]+b[2])*sc, (a[3]+b[3])*sc};
}

struct ETiles { f32x4 r0, r1, z0, z1, nx0, nx1; };

// One wave = 16 batch elements, swapped-operand MFMA (C[unit][elem]).
// Software-pipelined: e-side MFMA tiles for step t are built during step t-1;
// x prefetched 4 steps ahead. The serial chain is hB -> 6 h-MFMAs -> gates
// (exp2-native, weights prescaled) -> 2x permlane-swap -> hB.
__global__ __launch_bounds__(64) __attribute__((amdgpu_waves_per_eu(1, 1)))
void gru_encdec(
    const float* __restrict__ x,
    const float* __restrict__ W_emb, const float* __restrict__ b_emb,
    const float* __restrict__ Wih_e, const float* __restrict__ Whh_e,
    const float* __restrict__ bih_e, const float* __restrict__ bhh_e,
    const float* __restrict__ Wih_d, const float* __restrict__ Whh_d,
    const float* __restrict__ bih_d, const float* __restrict__ bhh_d,
    const float* __restrict__ W_out, const float* __restrict__ b_out,
    float* __restrict__ y)
{
    const int l = threadIdx.x;
    const int s = l & 15;
    const int g = l >> 4;
    const int w = blockIdx.x;

    // ---- encoder A-fragments (prescaled: r,z by log2e; n by 2log2e) ----
    const f16x8 Axr0 = loadAfrag(Wih_e,  0, s, g, L2E), Axr1 = loadAfrag(Wih_e, 16, s, g, L2E);
    const f16x8 Axz0 = loadAfrag(Wih_e, 32, s, g, L2E), Axz1 = loadAfrag(Wih_e, 48, s, g, L2E);
    const f16x8 Axn0 = loadAfrag(Wih_e, 64, s, g, N2E), Axn1 = loadAfrag(Wih_e, 80, s, g, N2E);
    const f16x8 Ahr0 = loadAfrag(Whh_e,  0, s, g, L2E), Ahr1 = loadAfrag(Whh_e, 16, s, g, L2E);
    const f16x8 Ahz0 = loadAfrag(Whh_e, 32, s, g, L2E), Ahz1 = loadAfrag(Whh_e, 48, s, g, L2E);
    const f16x8 Ahn0 = loadAfrag(Whh_e, 64, s, g, N2E), Ahn1 = loadAfrag(Whh_e, 80, s, g, N2E);

    const f32x4 Tbr0  = biasTile2(bih_e, bhh_e,  0, g, L2E), Tbr1 = biasTile2(bih_e, bhh_e, 16, g, L2E);
    const f32x4 Tbz0  = biasTile2(bih_e, bhh_e, 32, g, L2E), Tbz1 = biasTile2(bih_e, bhh_e, 48, g, L2E);
    const f32x4 Tbnx0 = biasTile(bih_e, 64, g, N2E), Tbnx1 = biasTile(bih_e, 80, g, N2E);
    const f32x4 Tbnh0 = biasTile(bhh_e, 64, g, N2E), Tbnh1 = biasTile(bhh_e, 80, g, N2E);

    // ---- embedder weights (unscaled; e is an activation) ----
    f16x2 wemb[8][2]; float bemb8[8];
    #pragma unroll
    for (int kk = 0; kk < 8; ++kk) {
        const f32x4 v = *(const f32x4*)(W_emb + (size_t)(g * 8 + kk) * 4);
        wemb[kk][0] = pkrtz(v[0], v[1]);
        wemb[kk][1] = pkrtz(v[2], v[3]);
        bemb8[kk] = b_emb[g * 8 + kk];
    }

    const f32x4* xb = (const f32x4*)x + (size_t)(w * ELW + s) * T_LEN;

    auto make_eB = [&](const f32x4 xv) -> f16x8 {
        const f16x2 xp01 = pkrtz(xv[0], xv[1]);
        const f16x2 xp23 = pkrtz(xv[2], xv[3]);
        float ev[8];
        #pragma unroll
        for (int kk = 0; kk < 8; ++kk)
            ev[kk] = fmaxf(dot2(wemb[kk][0], xp01, dot2(wemb[kk][1], xp23, bemb8[kk])), 0.0f);
        F16x8U e;
        #pragma unroll
        for (int q = 0; q < 4; ++q)
            e.d[q] = pkbits(ev[2 * q], ev[2 * q + 1]);
        return e.v;
    };
    auto make_E = [&](f16x8 eB) -> ETiles {
        ETiles E;
        E.nx0 = MF(Axn0, eB, Tbnx0); E.nx1 = MF(Axn1, eB, Tbnx1);
        E.r0  = MF(Axr0, eB, Tbr0);  E.r1  = MF(Axr1, eB, Tbr1);
        E.z0  = MF(Axz0, eB, Tbz0);  E.z1  = MF(Axz1, eB, Tbz1);
        return E;
    };

    F16x8U hB; hB.d[0] = 0; hB.d[1] = 0; hB.d[2] = 0; hB.d[3] = 0;
    f32x4 hc0 = {0.f, 0.f, 0.f, 0.f};
    f32x4 hc1 = {0.f, 0.f, 0.f, 0.f};

    // ---- pipeline prologue ----
    f32x4 x0 = xb[0], x1 = xb[1], xc = xb[2], xd = xb[3];
    ETiles E = make_E(make_eB(x0));   // e-tiles for step 0
    f16x8 eBn = make_eB(x1);          // e-fragment for step 1

    // ---- encoder: 512 steps ----
    #pragma unroll 1
    for (int t = 0; t < T_LEN; ++t) {
        // chain head: h-MFMAs (n-path first, z last)
        const f32x4 cnh0 = MF(Ahn0, hB.v, Tbnh0), cnh1 = MF(Ahn1, hB.v, Tbnh1);
        const f32x4 cr0  = MF(Ahr0, hB.v, E.r0),  cr1  = MF(Ahr1, hB.v, E.r1);
        const f32x4 cz0  = MF(Ahz0, hB.v, E.z0),  cz1  = MF(Ahz1, hB.v, E.z1);
        const f32x4 cnx0 = E.nx0, cnx1 = E.nx1;
        // off-chain: next step's e-tiles + next-next e-fragment + x prefetch
        E = make_E(eBn);
        eBn = make_eB(xc);
        xc = xd;
        int ti = t + 4; ti = ti < T_LEN ? ti : T_LEN - 1;
        xd = xb[ti];
        // gates (prescaled inputs, native exp2)
        #pragma unroll
        for (int i = 0; i < 4; ++i) {
            const float r0 = sig_s(cr0[i]), z0 = sig_s(cz0[i]);
            const float n0 = tanh_s(fmaf(r0, cnh0[i], cnx0[i]));
            hc0[i] = fmaf(z0, hc0[i] - n0, n0);
            const float r1 = sig_s(cr1[i]), z1 = sig_s(cz1[i]);
            const float n1 = tanh_s(fmaf(r1, cnh1[i], cnx1[i]));
            hc1[i] = fmaf(z1, hc1[i] - n1, n1);
        }
        // C-layout -> B-fragment (all-VALU transpose)
        unsigned p0 = pkbits(hc0[0], hc0[1]), p1 = pkbits(hc0[2], hc0[3]);
        unsigned q0 = pkbits(hc1[0], hc1[1]), q1 = pkbits(hc1[2], hc1[3]);
        swap32(p0, q0); swap32(p1, q1);
        swap16(p0, q0); swap16(p1, q1);
        hB.d[0] = p0; hB.d[1] = p1; hB.d[2] = q0; hB.d[3] = q1;
    }

    // ---- decoder A-fragments (r,z presummed; prescaled) + W_out ----
    const f16x8 Adr0 = loadAfragSum(Wih_d, Whh_d,  0, s, g, L2E);
    const f16x8 Adr1 = loadAfragSum(Wih_d, Whh_d, 16, s, g, L2E);
    const f16x8 Adz0 = loadAfragSum(Wih_d, Whh_d, 32, s, g, L2E);
    const f16x8 Adz1 = loadAfragSum(Wih_d, Whh_d, 48, s, g, L2E);
    const f16x8 Adnx0 = loadAfrag(Wih_d, 64, s, g, N2E), Adnx1 = loadAfrag(Wih_d, 80, s, g, N2E);
    const f16x8 Adnh0 = loadAfrag(Whh_d, 64, s, g, N2E), Adnh1 = loadAfrag(Whh_d, 80, s, g, N2E);
    f16x8 Aout = {};
    if (s < 4) Aout = loadAfrag(W_out, 0, s, g, 1.0f);
    const f32x4 Tdr0  = biasTile2(bih_d, bhh_d,  0, g, L2E), Tdr1 = biasTile2(bih_d, bhh_d, 16, g, L2E);
    const f32x4 Tdz0  = biasTile2(bih_d, bhh_d, 32, g, L2E), Tdz1 = biasTile2(bih_d, bhh_d, 48, g, L2E);
    const f32x4 Tdnx0 = biasTile(bih_d, 64, g, N2E), Tdnx1 = biasTile(bih_d, 80, g, N2E);
    const f32x4 Tdnh0 = biasTile(bhh_d, 64, g, N2E), Tdnh1 = biasTile(bhh_d, 80, g, N2E);
    const f32x4 Tby = (g == 0) ? *(const f32x4*)b_out : (f32x4){0.f, 0.f, 0.f, 0.f};

    // ---- decoder: 60 steps ----
    #pragma unroll 1
    for (int f = 0; f < FUT; ++f) {
        const f32x4 cnh0 = MF(Adnh0, hB.v, Tdnh0), cnh1 = MF(Adnh1, hB.v, Tdnh1);
        const f32x4 cr0  = MF(Adr0, hB.v, Tdr0),   cr1  = MF(Adr1, hB.v, Tdr1);
        const f32x4 cnx0 = MF(Adnx0, hB.v, Tdnx0), cnx1 = MF(Adnx1, hB.v, Tdnx1);
        const f32x4 cz0  = MF(Adz0, hB.v, Tdz0),   cz1  = MF(Adz1, hB.v, Tdz1);
        #pragma unroll
        for (int i = 0; i < 4; ++i) {
            const float r0 = sig_s(cr0[i]), z0 = sig_s(cz0[i]);
            const float n0 = tanh_s(fmaf(r0, cnh0[i], cnx0[i]));
            hc0[i] = fmaf(z0, hc0[i] - n0, n0);
            const float r1 = sig_s(cr1[i]), z1 = sig_s(cz1[i]);
            const float n1 = tanh_s(fmaf(r1, cnh1[i], cnx1[i]));
            hc1[i] = fmaf(z1, hc1[i] - n1, n1);
        }
        unsigned p0 = pkbits(hc0[0], hc0[1]), p1 = pkbits(hc0[2], hc0[3]);
        unsigned q0 = pkbits(hc1[0], hc1[1]), q1 = pkbits(hc1[2], hc1[3]);
        swap32(p0, q0); swap32(p1, q1);
        swap16(p0, q0); swap16(p1, q1);
        hB.d[0] = p0; hB.d[1] = p1; hB.d[2] = q0; hB.d[3] = q1;

        const f32x4 cy = MF(Aout, hB.v, Tby);
        if (g == 0)
            *(f32x4*)(y + ((size_t)(w * ELW + s) * FUT + f) * 4) = cy;
    }
}

extern "C" void kernel_launch(void* const* d_in, const int* in_sizes, int n_in,
                              void* d_out, int out_size, void* d_ws, size_t ws_size,
                              hipStream_t stream) {
    (void)in_sizes; (void)n_in; (void)d_ws; (void)ws_size; (void)out_size;
    gru_encdec<<<dim3(2048 / ELW), dim3(64), 0, stream>>>(
        (const float*)d_in[0],                            // x
        (const float*)d_in[1],  (const float*)d_in[2],    // W_emb, b_emb
        (const float*)d_in[3],  (const float*)d_in[4],    // Wih_e, Whh_e
        (const float*)d_in[5],  (const float*)d_in[6],    // bih_e, bhh_e
        (const float*)d_in[7],  (const float*)d_in[8],    // Wih_d, Whh_d
        (const float*)d_in[9],  (const float*)d_in[10],   // bih_d, bhh_d
        (const float*)d_in[11], (const float*)d_in[12],   // W_out, b_out
        (float*)d_out);
}